// Round 8
// baseline (32.054 us; speedup 1.0000x reference)
//
#include <hip/hip_runtime.h>

#define NBITS 13
#define DMODEL 1024
#define PPB 16       // positions per block (main kernel)
#define LUT_LO 128   // 2^7 combinations of bits 0..6
#define LUT_HI 64    // 2^6 combinations of bits 7..12
#define LUT_ROWS (LUT_LO + LUT_HI)

typedef float v4f __attribute__((ext_vector_type(4)));

// ---- Kernel 1: build split LUT in workspace (192 rows x 4 KB = 768 KB) ----
// lut[v]        (v<128):  sum of emb[b] for set bits b of v, b in 0..6
// lut[128+v]    (v<64):   sum of emb[7+b] for set bits b of v, b in 0..5
__global__ __launch_bounds__(256) void lut_build(const float* __restrict__ emb,
                                                 float* __restrict__ lut) {
    const int r = blockIdx.x;   // 0..191
    const int t = threadIdx.x;  // owns columns 4t..4t+3
    v4f acc = {0.f, 0.f, 0.f, 0.f};
    if (r < LUT_LO) {
#pragma unroll
        for (int b = 0; b < 7; ++b) {
            const float m = __int_as_float(((r >> b) & 1) ? 0x3f800000 : 0);
            const v4f e = *reinterpret_cast<const v4f*>(emb + b * DMODEL + t * 4);
            acc.x = fmaf(m, e.x, acc.x);
            acc.y = fmaf(m, e.y, acc.y);
            acc.z = fmaf(m, e.z, acc.z);
            acc.w = fmaf(m, e.w, acc.w);
        }
    } else {
        const int v = r - LUT_LO;
#pragma unroll
        for (int b = 0; b < 6; ++b) {
            const float m = __int_as_float(((v >> b) & 1) ? 0x3f800000 : 0);
            const v4f e = *reinterpret_cast<const v4f*>(emb + (7 + b) * DMODEL + t * 4);
            acc.x = fmaf(m, e.x, acc.x);
            acc.y = fmaf(m, e.y, acc.y);
            acc.z = fmaf(m, e.z, acc.z);
            acc.w = fmaf(m, e.w, acc.w);
        }
    }
    *reinterpret_cast<v4f*>(lut + (size_t)r * DMODEL + t * 4) = acc;
}

// ---- Kernel 2: out[p] = lut[x&127] + lut[128 + (x>>7)] ------------------
// Per position: 2 coalesced 16B L2-hot loads + 4 adds + 1 store. No frag
// registers, no per-block setup -> store stream is nearly pure.
__global__ __launch_bounds__(256) void bpe_lut_kernel(const int* __restrict__ x,
                                                      const float* __restrict__ lut,
                                                      float* __restrict__ out,
                                                      int npos) {
    const int t = threadIdx.x;
    const int base = blockIdx.x * PPB;
    const float* hi = lut + (size_t)LUT_LO * DMODEL;

    if (base + PPB <= npos) {
        int xv[PPB];
#pragma unroll
        for (int i = 0; i < PPB; i += 4) {
            const int4 v = *reinterpret_cast<const int4*>(x + base + i);
            xv[i + 0] = v.x;
            xv[i + 1] = v.y;
            xv[i + 2] = v.z;
            xv[i + 3] = v.w;
        }
        float* o = out + (size_t)base * DMODEL + (size_t)(t * 4);
#pragma unroll
        for (int i = 0; i < PPB; ++i) {
            const int v = xv[i];
            const v4f a = *reinterpret_cast<const v4f*>(
                lut + (size_t)(v & (LUT_LO - 1)) * DMODEL + t * 4);
            const v4f b = *reinterpret_cast<const v4f*>(
                hi + (size_t)(v >> 7) * DMODEL + t * 4);
            const v4f s = a + b;
            *reinterpret_cast<v4f*>(o + (size_t)i * DMODEL) = s;
        }
    } else {
        for (int p = base; p < npos; ++p) {
            const int v = x[p];
            const v4f a = *reinterpret_cast<const v4f*>(
                lut + (size_t)(v & (LUT_LO - 1)) * DMODEL + t * 4);
            const v4f b = *reinterpret_cast<const v4f*>(
                hi + (size_t)(v >> 7) * DMODEL + t * 4);
            const v4f s = a + b;
            *reinterpret_cast<v4f*>(out + (size_t)p * DMODEL + (size_t)(t * 4)) = s;
        }
    }
}

// ---- Fallback (R4 structure) if ws_size ever too small ------------------
__global__ __launch_bounds__(256) void bpe_direct_kernel(const int* __restrict__ x,
                                                         const float* __restrict__ emb,
                                                         float* __restrict__ out,
                                                         int npos) {
    const int t = threadIdx.x;
    v4f frag[NBITS];
#pragma unroll
    for (int b = 0; b < NBITS; ++b) {
        frag[b] = *reinterpret_cast<const v4f*>(emb + b * DMODEL + t * 4);
    }
    for (int p = blockIdx.x; p < npos; p += gridDim.x) {
        const int v = x[p];
        v4f acc = {0.f, 0.f, 0.f, 0.f};
#pragma unroll
        for (int b = 0; b < NBITS; ++b) {
            const float m = __int_as_float(((v >> b) & 1) ? 0x3f800000 : 0);
            acc.x = fmaf(m, frag[b].x, acc.x);
            acc.y = fmaf(m, frag[b].y, acc.y);
            acc.z = fmaf(m, frag[b].z, acc.z);
            acc.w = fmaf(m, frag[b].w, acc.w);
        }
        *reinterpret_cast<v4f*>(out + (size_t)p * DMODEL + (size_t)(t * 4)) = acc;
    }
}

extern "C" void kernel_launch(void* const* d_in, const int* in_sizes, int n_in,
                              void* d_out, int out_size, void* d_ws, size_t ws_size,
                              hipStream_t stream) {
    const int* x = (const int*)d_in[0];        // (4, 8192) int32, flat 32768
    const float* emb = (const float*)d_in[1];  // (13, 1024) float32
    float* out = (float*)d_out;                // (4, 8192, 1024) float32
    const int npos = in_sizes[0];              // 32768

    const size_t lut_bytes = (size_t)LUT_ROWS * DMODEL * sizeof(float);  // 768 KB
    if (ws_size >= lut_bytes) {
        float* lut = (float*)d_ws;
        lut_build<<<LUT_ROWS, 256, 0, stream>>>(emb, lut);
        const int grid = (npos + PPB - 1) / PPB;  // 2048
        bpe_lut_kernel<<<grid, 256, 0, stream>>>(x, lut, out, npos);
    } else {
        int grid = npos < 2048 ? npos : 2048;
        bpe_direct_kernel<<<grid, 256, 0, stream>>>(x, emb, out, npos);
    }
}

// Round 9
// 27.644 us; speedup vs baseline: 1.1595x; 1.1595x over previous
//
#include <hip/hip_runtime.h>

#define NBITS 13
#define DMODEL 1024
#define PPB 16  // positions per block: 16 x 4 KB = 64 KB contiguous output/block

typedef float v4f __attribute__((ext_vector_type(4)));

// out[p, d] = sum over set bits b of x[p] of emb[b, d]
// Empirical best (R4): one block = 16 consecutive positions, fully unrolled.
// emb slice hoisted to 52 VGPRs once per block; fresh accumulator per position
// so stores are fire-and-forget (no vmcnt register-reuse waits); 16 independent
// global_store_dwordx4 streams per wave; cached (non-NT) stores.
// Tested and rejected: NT stores (-27%), PPB=32 (-4%), float2/512t (-16%),
// split-LUT (-21% incl. extra launch). This structure is write-BW-bound:
// 134 MB / 6.3 TB/s achievable + ~3 us launch/ramp ~= 24-25 us floor.
__global__ __launch_bounds__(256) void bpe_kernel(const int* __restrict__ x,
                                                  const float* __restrict__ emb,
                                                  float* __restrict__ out,
                                                  int npos) {
    const int t = threadIdx.x;  // owns columns 4t..4t+3

    // 13 x float4 = 52 VGPRs of emb slice, loaded once per block (L2-hit).
    v4f frag[NBITS];
#pragma unroll
    for (int b = 0; b < NBITS; ++b) {
        frag[b] = *reinterpret_cast<const v4f*>(emb + b * DMODEL + t * 4);
    }

    const int base = blockIdx.x * PPB;

    if (base + PPB <= npos) {
        // All 16 x values up front: uniform addresses -> scalar dwordx4 loads.
        int xv[PPB];
#pragma unroll
        for (int i = 0; i < PPB; i += 4) {
            const int4 v = *reinterpret_cast<const int4*>(x + base + i);
            xv[i + 0] = v.x;
            xv[i + 1] = v.y;
            xv[i + 2] = v.z;
            xv[i + 3] = v.w;
        }

        float* o = out + (size_t)base * DMODEL + (size_t)(t * 4);
#pragma unroll
        for (int i = 0; i < PPB; ++i) {
            const int v = xv[i];
            v4f acc = {0.f, 0.f, 0.f, 0.f};
#pragma unroll
            for (int b = 0; b < NBITS; ++b) {
                // 1.0f/0.0f multiplier via uniform bit select (s_cselect).
                const float m = __int_as_float(((v >> b) & 1) ? 0x3f800000 : 0);
                acc.x = fmaf(m, frag[b].x, acc.x);
                acc.y = fmaf(m, frag[b].y, acc.y);
                acc.z = fmaf(m, frag[b].z, acc.z);
                acc.w = fmaf(m, frag[b].w, acc.w);
            }
            // Fresh registers every position: store never blocks later compute.
            *reinterpret_cast<v4f*>(o + (size_t)i * DMODEL) = acc;
        }
    } else {
        // Tail (npos % 16 != 0) — not hit for npos=32768.
        for (int p = base; p < npos; ++p) {
            const int v = x[p];
            v4f acc = {0.f, 0.f, 0.f, 0.f};
#pragma unroll
            for (int b = 0; b < NBITS; ++b) {
                const float m = __int_as_float(((v >> b) & 1) ? 0x3f800000 : 0);
                acc.x = fmaf(m, frag[b].x, acc.x);
                acc.y = fmaf(m, frag[b].y, acc.y);
                acc.z = fmaf(m, frag[b].z, acc.z);
                acc.w = fmaf(m, frag[b].w, acc.w);
            }
            *reinterpret_cast<v4f*>(out + (size_t)p * DMODEL + (size_t)(t * 4)) = acc;
        }
    }
}

extern "C" void kernel_launch(void* const* d_in, const int* in_sizes, int n_in,
                              void* d_out, int out_size, void* d_ws, size_t ws_size,
                              hipStream_t stream) {
    const int* x = (const int*)d_in[0];        // (4, 8192) int32, flat 32768
    const float* emb = (const float*)d_in[1];  // (13, 1024) float32
    float* out = (float*)d_out;                // (4, 8192, 1024) float32

    const int npos = in_sizes[0];  // 32768

    const int grid = (npos + PPB - 1) / PPB;   // 2048 blocks for npos=32768
    bpe_kernel<<<grid, 256, 0, stream>>>(x, emb, out, npos);
}